// Round 5
// baseline (302.047 us; speedup 1.0000x reference)
//
#include <hip/hip_runtime.h>
#include <math.h>

// MPN-COV: cov = (X X^T - S S^T/N)/(N-1); sqrt via coupled Newton-Schulz
// (4 iters, trace-normalized, Z0=I shortcut); triu-pack fused into final
// NS epilogue. Trace+init fused into gram via last-block-per-batch.
// B=64, C=256, N=4096.  ws ~= 1 GiB.

#define B_ 64
#define C_ 256
#define N_ 4096
#define TRI ((C_*(C_+1))/2)
#define MATE (C_*C_)
#define TOTE ((size_t)B_*MATE)
#define KS 4
#define KW (N_/KS)              // 1024

typedef __attribute__((ext_vector_type(8))) short bf16x8;
typedef __attribute__((ext_vector_type(4))) short short4v;
typedef __attribute__((ext_vector_type(4))) float f32x4;

__device__ __forceinline__ short f2bf(float f) {        // RNE float->bf16
    unsigned u = __float_as_uint(f);
    return (short)((u + 0x7FFFu + ((u >> 16) & 1u)) >> 16);
}
__device__ __forceinline__ float bf2f(short s) {
    return __uint_as_float(((unsigned)(unsigned short)s) << 16);
}
__device__ __forceinline__ void gload_lds16(const void* g, void* l) {
    __builtin_amdgcn_global_load_lds(
        (const __attribute__((address_space(1))) void*)g,
        (__attribute__((address_space(3))) void*)l, 16, 0, 0);
}

// ================= gram + cov + trace + init (fused) =================
// grid 256 = 64 batches x 4 K-slabs (KW=1024). 512 threads = 8 waves (2x4),
// wave computes 128x64 of the 256x256 output; X-slab staged once (dbuf).
// Last block per batch (device-scope atomic) reduces partials, computes
// m = tr(cov)/C, writes Y0 = cov/m and Z1 = 1.5I - 0.5*Y0 (both bf16).
__global__ __launch_bounds__(512, 1) void gram_cov(const float* __restrict__ x,
                                                   float* __restrict__ Gp,
                                                   float* __restrict__ Sp,
                                                   int* __restrict__ cnt,
                                                   float* __restrict__ mArr,
                                                   short* __restrict__ Y0,
                                                   short* __restrict__ Z1) {
    int bid = (blockIdx.x & 7) * 32 + (blockIdx.x >> 3);   // XCD swizzle (256)
    int b = bid >> 2, slab = bid & 3;
    const float* xb = x + (size_t)b * C_ * N_ + (size_t)slab * KW;

    __shared__ short Xs[2][16384];      // [dbuf][256 rows][64 k] bf16, swizzled
    __shared__ float Sred[256][16];
    __shared__ float Stot[256];
    __shared__ float red2[256];
    __shared__ int lastFlag;

    int tid = threadIdx.x;
    int lane = tid & 63, wid = tid >> 6;
    int wr = wid >> 2, wc = wid & 3;    // 2 x 4 wave grid
    int lr = lane & 15, hi = lane >> 4;
    int srow = tid >> 4;                // 0..31
    int scol = (tid & 15) * 4;          // 0..60 (floats)

    float ps[8] = {};
    f32x4 acc[8][4] = {};
    f32x4 rv[8];

    #pragma unroll
    for (int q = 0; q < 8; ++q)
        rv[q] = *(const f32x4*)(xb + (size_t)(q * 32 + srow) * N_ + scol);
    #pragma unroll
    for (int q = 0; q < 8; ++q) {
        int row = q * 32 + srow;
        ps[q] += rv[q][0] + rv[q][1] + rv[q][2] + rv[q][3];
        short4v o;
        #pragma unroll
        for (int e = 0; e < 4; ++e) o[e] = f2bf(rv[q][e]);
        *(short4v*)((char*)Xs[0] + row * 128 + ((scol * 2) ^ ((row & 7) << 4))) = o;
    }
    __syncthreads();

    const int NSTEP = KW / 64;          // 16
    for (int c = 0; c < NSTEP; ++c) {
        if (c + 1 < NSTEP) {            // issue next loads early (T14)
            #pragma unroll
            for (int q = 0; q < 8; ++q)
                rv[q] = *(const f32x4*)(xb + (size_t)(q * 32 + srow) * N_ + (c + 1) * 64 + scol);
        }
        const char* Xb = (const char*)Xs[c & 1];
        #pragma unroll
        for (int ks2 = 0; ks2 < 2; ++ks2) {
            bf16x8 af[8], bfr[4];
            #pragma unroll
            for (int m = 0; m < 8; ++m) {
                int row = wr * 128 + m * 16 + lr;
                af[m] = *(const bf16x8*)(Xb + row * 128 + ((ks2 * 64 + hi * 16) ^ ((row & 7) << 4)));
            }
            #pragma unroll
            for (int n = 0; n < 4; ++n) {
                int row = wc * 64 + n * 16 + lr;
                bfr[n] = *(const bf16x8*)(Xb + row * 128 + ((ks2 * 64 + hi * 16) ^ ((row & 7) << 4)));
            }
            #pragma unroll
            for (int m = 0; m < 8; ++m)
                #pragma unroll
                for (int n = 0; n < 4; ++n)
                    acc[m][n] = __builtin_amdgcn_mfma_f32_16x16x32_bf16(af[m], bfr[n], acc[m][n], 0, 0, 0);
        }
        if (c + 1 < NSTEP) {
            #pragma unroll
            for (int q = 0; q < 8; ++q) {
                int row = q * 32 + srow;
                ps[q] += rv[q][0] + rv[q][1] + rv[q][2] + rv[q][3];
                short4v o;
                #pragma unroll
                for (int e = 0; e < 4; ++e) o[e] = f2bf(rv[q][e]);
                *(short4v*)((char*)Xs[(c + 1) & 1] + row * 128 + ((scol * 2) ^ ((row & 7) << 4))) = o;
            }
        }
        __syncthreads();
    }

    // partial row sums for this K-slab
    #pragma unroll
    for (int q = 0; q < 8; ++q) Sred[q * 32 + srow][tid & 15] = ps[q];
    __syncthreads();
    if (tid < 256) {
        float s = 0.f;
        #pragma unroll
        for (int e = 0; e < 16; ++e) s += Sred[tid][e];
        Sp[((size_t)slab * B_ + b) * C_ + tid] = s;
    }

    // partial gram (fp32)
    float* G = Gp + ((size_t)slab * B_ + b) * MATE;
    #pragma unroll
    for (int m = 0; m < 8; ++m)
        #pragma unroll
        for (int n = 0; n < 4; ++n)
            #pragma unroll
            for (int r = 0; r < 4; ++r) {
                int i = wr * 128 + m * 16 + hi * 4 + r;
                int j = wc * 64 + n * 16 + lr;
                G[(size_t)i * C_ + j] = acc[m][n][r];
            }

    // ---- last-block-per-batch finisher ----
    __threadfence();                                   // release partials
    if (tid == 0) lastFlag = (atomicAdd(&cnt[b], 1) == KS - 1);
    __syncthreads();
    if (!lastFlag) return;
    __threadfence();                                   // acquire (all threads)

    if (tid < 256) {
        float s = 0.f, g = 0.f;
        #pragma unroll
        for (int sl = 0; sl < KS; ++sl) {
            s += Sp[((size_t)sl * B_ + b) * C_ + tid];
            g += Gp[((size_t)sl * B_ + b) * MATE + (size_t)tid * (C_ + 1)];
        }
        Stot[tid] = s;
        red2[tid] = (g - s * s * (1.0f / N_)) * (1.0f / (N_ - 1));
    }
    __syncthreads();
    for (int off = 128; off; off >>= 1) {
        if (tid < off) red2[tid] += red2[tid + off];
        __syncthreads();
    }
    float m = red2[0] * (1.0f / C_);
    float invm = 1.0f / m;
    if (tid == 0) { mArr[b] = m; mArr[64 + b] = invm; mArr[128 + b] = sqrtf(m); }

    for (int ch = tid; ch < MATE / 4; ch += 512) {
        int e = ch * 4;
        int i = e >> 8, j0 = e & 255;
        f32x4 g = {};
        #pragma unroll
        for (int sl = 0; sl < KS; ++sl) {
            f32x4 t = *(const f32x4*)(Gp + ((size_t)sl * B_ + b) * MATE + e);
            g[0] += t[0]; g[1] += t[1]; g[2] += t[2]; g[3] += t[3];
        }
        float Si = Stot[i];
        const float invN = 1.0f / (float)N_;
        const float invN1 = 1.0f / (float)(N_ - 1);
        short4v y, z;
        #pragma unroll
        for (int q = 0; q < 4; ++q) {
            float cov = (g[q] - Si * Stot[j0 + q] * invN) * invN1;
            float a = cov * invm;
            y[q] = f2bf(a);
            z[q] = f2bf(((i == j0 + q) ? 1.5f : 0.0f) - 0.5f * a);
        }
        *(short4v*)(Y0 + (size_t)b * MATE + e) = y;
        *(short4v*)(Z1 + (size_t)b * MATE + e) = z;
    }
}

// ================= NS GEMM (K=256, panels fully in LDS) =================
// acc[i,j] = sum_k A[i,k]*B[j,k]  (all iterates symmetric -> NT form)
// EP: 0 = P bf16 (acc); 1 = YZ' bf16 (1.5*Base - 0.5*acc), optional dual;
//     2 = final: out[b, triu(i,j)] = sqrt(m)*(1.5*Base - 0.5*acc), upper tiles
template<int EP, bool DUAL>
__global__ __launch_bounds__(256, 1) void ns_gemm(
        const short* A0, const short* B0, const short* Ba0, void* C0,
        const short* A1, const short* B1, const short* Ba1, void* C1,
        const float* __restrict__ mArr) {
    int nb = gridDim.x, per = nb >> 3;
    int bid = (blockIdx.x & 7) * per + (blockIdx.x >> 3);  // XCD swizzle
    const short *A = A0, *B = B0, *Ba = Ba0; void* C = C0;
    if (DUAL && bid >= (nb >> 1)) { bid -= nb >> 1; A = A1; B = B1; Ba = Ba1; C = C1; }
    int b, ti, tj;
    if constexpr (EP == 2) {
        b = bid / 3; int t = bid % 3;
        ti = (t == 2) ? 1 : 0; tj = (t == 0) ? 0 : 1;     // (0,0),(0,1),(1,1)
    } else {
        b = bid >> 2; int t = bid & 3;
        ti = t >> 1; tj = t & 1;
    }
    const short* Ap = A + (size_t)b * MATE + (size_t)ti * 128 * C_;
    const short* Bp = B + (size_t)b * MATE + (size_t)tj * 128 * C_;

    __shared__ short As[32768], Bs[32768];   // 64KB each, swizzled layout

    int tid = threadIdx.x, lane = tid & 63, wid = tid >> 6;
    // stage: linear LDS dest, inverse-swizzled global source (rule #21)
    #pragma unroll
    for (int j = 0; j < 16; ++j) {
        int slot = (j * 4 + wid) * 64 + lane;
        int d = slot * 16;
        int row = d >> 9;
        int inner = (d & 511) ^ ((row & 7) << 4);
        gload_lds16((const char*)Ap + (size_t)row * 512 + inner,
                    (char*)As + (size_t)(j * 4 + wid) * 1024);
        gload_lds16((const char*)Bp + (size_t)row * 512 + inner,
                    (char*)Bs + (size_t)(j * 4 + wid) * 1024);
    }
    __syncthreads();

    int wr = wid >> 1, wc = wid & 1;
    int lr = lane & 15, hi = lane >> 4;
    f32x4 acc[4][4] = {};
    #pragma unroll
    for (int ks = 0; ks < 8; ++ks) {
        bf16x8 af[4], bb[4];
        #pragma unroll
        for (int m = 0; m < 4; ++m) {
            int rowa = wr * 64 + m * 16 + lr;
            af[m] = *(const bf16x8*)((const char*)As + rowa * 512 + ((ks * 64 + hi * 16) ^ ((rowa & 7) << 4)));
            int rowb = wc * 64 + m * 16 + lr;
            bb[m] = *(const bf16x8*)((const char*)Bs + rowb * 512 + ((ks * 64 + hi * 16) ^ ((rowb & 7) << 4)));
        }
        #pragma unroll
        for (int m = 0; m < 4; ++m)
            #pragma unroll
            for (int n = 0; n < 4; ++n)
                acc[m][n] = __builtin_amdgcn_mfma_f32_16x16x32_bf16(af[m], bb[n], acc[m][n], 0, 0, 0);
    }

    int r0 = hi * 4;
    float sqm = (EP == 2) ? mArr[128 + b] : 0.f;
    #pragma unroll
    for (int m = 0; m < 4; ++m)
        #pragma unroll
        for (int n = 0; n < 4; ++n)
            #pragma unroll
            for (int r = 0; r < 4; ++r) {
                int i = ti * 128 + wr * 64 + m * 16 + r0 + r;
                int j = tj * 128 + wc * 64 + n * 16 + lr;
                size_t idx = (size_t)b * MATE + (size_t)i * C_ + j;
                float v = acc[m][n][r];
                if constexpr (EP == 0) {
                    ((short*)C)[idx] = f2bf(v);
                } else if constexpr (EP == 1) {
                    ((short*)C)[idx] = f2bf(1.5f * bf2f(Ba[idx]) - 0.5f * v);
                } else {
                    if (j >= i) {
                        size_t o = (size_t)b * TRI + (size_t)i * C_ - (size_t)(i * (i - 1)) / 2 + (j - i);
                        ((float*)C)[o] = sqm * (1.5f * bf2f(Ba[idx]) - 0.5f * v);
                    }
                }
            }
}

extern "C" void kernel_launch(void* const* d_in, const int* in_sizes, int n_in,
                              void* d_out, int out_size, void* d_ws, size_t ws_size,
                              hipStream_t stream) {
    const float* x = (const float*)d_in[0];
    float* out = (float*)d_out;

    int* cnt    = (int*)d_ws;                      // 64 ints
    float* mArr = (float*)d_ws + 64;               // 192 floats used
    float* Sp   = mArr + 192;                      // KS*B*C = 65536
    float* Gp   = Sp + (size_t)KS * B_ * C_;       // KS*TOTE fp32 = 64MB
    short* bufs = (short*)(Gp + (size_t)KS * TOTE);
    short* M0 = bufs;                              // 5 bf16 matrices, 8MB each
    short* M1 = bufs + TOTE;
    short* M2 = bufs + 2 * TOTE;
    short* M3 = bufs + 3 * TOTE;
    short* M4 = bufs + 4 * TOTE;

    hipMemsetAsync(cnt, 0, 64 * sizeof(int), stream);

    // gram + cov + trace + init: Y0 -> M0, Z1 = 1.5I - 0.5*Y0 -> M1
    gram_cov<<<B_ * KS, 512, 0, stream>>>(x, Gp, Sp, cnt, mArr, M0, M1);

    // it1 (Z0=I shortcut): Y1 = 1.5*Y0 - 0.5*Y0*Y0 -> M2
    ns_gemm<1, false><<<256, 256, 0, stream>>>(M0, M0, M0, M2,
                                               nullptr, nullptr, nullptr, nullptr, nullptr);
    // it2: P1 = Z1*Y1 -> M3
    ns_gemm<0, false><<<256, 256, 0, stream>>>(M1, M2, nullptr, M3,
                                               nullptr, nullptr, nullptr, nullptr, nullptr);
    //      Y2 = 1.5Y1 - 0.5*Y1*P1 -> M4 || Z2 = 1.5Z1 - 0.5*P1*Z1 -> M0
    ns_gemm<1, true><<<512, 256, 0, stream>>>(M2, M3, M2, M4,
                                              M3, M1, M1, M0, nullptr);
    // it3: P2 = Z2*Y2 -> M2
    ns_gemm<0, false><<<256, 256, 0, stream>>>(M0, M4, nullptr, M2,
                                               nullptr, nullptr, nullptr, nullptr, nullptr);
    //      Y3 = 1.5Y2 - 0.5*Y2*P2 -> M3 || Z3 = 1.5Z2 - 0.5*P2*Z2 -> M1
    ns_gemm<1, true><<<512, 256, 0, stream>>>(M4, M2, M4, M3,
                                              M2, M0, M0, M1, nullptr);
    // it4: P3 = Z3*Y3 -> M4
    ns_gemm<0, false><<<256, 256, 0, stream>>>(M1, M3, nullptr, M4,
                                               nullptr, nullptr, nullptr, nullptr, nullptr);
    //      final: out = sqrt(m)*(1.5Y3 - 0.5*Y3*P3), triu-packed, upper tiles
    ns_gemm<2, false><<<B_ * 3, 256, 0, stream>>>(M3, M4, M3, out,
                                                  nullptr, nullptr, nullptr, nullptr, mArr);
}